// Round 20
// baseline (267.522 us; speedup 1.0000x reference)
//
#include <hip/hip_runtime.h>
#include <stdint.h>

// ---------------- problem constants (fixed by harness) ----------------
static constexpr int BATCH = 8;
static constexpr int NTOK  = 4096;          // 64*64
static constexpr int CDIM  = 512;
static constexpr int NCOL  = 1024;          // 2C
static constexpr int MROWS = BATCH * NTOK;  // 32768
static constexpr int KDIM  = 512;

// ---------------- workspace layout ----------------
static constexpr size_t OFF_KSUM = 0;                         // 8*512 f32        = 16384 B
static constexpr size_t OFF_KV   = 16384;                     // 8*16*32*32 f32   = 524288 B
static constexpr size_t OFF_XB   = 540672;                    // bf16 x           = 33554432 B
static constexpr size_t OFF_WT   = OFF_XB + 33554432;         // bf16 W^T         = 1048576 B
static constexpr size_t OFF_QP   = OFF_WT + 1048576;          // bf16 q_plain     = 33554432 B
static constexpr size_t OFF_KR   = OFF_QP + 33554432;         // bf16 k_rope      = 33554432 B
static constexpr size_t OFF_TRIG = OFF_KR + 33554432;         // 64*128 float2    = 65536 B
static constexpr size_t OFF_WT9  = OFF_TRIG + 65536;          // 9*512 f32        = 18432 B
static constexpr size_t WS_NEED  = OFF_WT9 + 18432;           // ~102.4 MB

// kv constants (32 chunks of 128 rows; direct atomic accumulation into kv)
static constexpr int KV_CHUNKS = 32;

// ---------------- helpers ----------------
typedef __attribute__((ext_vector_type(8))) short bf16x8;
typedef __attribute__((ext_vector_type(4))) float f32x4;
typedef __attribute__((ext_vector_type(8))) unsigned short u16x8;

__device__ __forceinline__ float bf2f(unsigned short u) {
  union { unsigned int i; float f; } v; v.i = ((unsigned int)u) << 16; return v.f;
}
__device__ __forceinline__ unsigned short f2bf(float f) {
  union { float f; unsigned int i; } v; v.f = f;
  unsigned int b = v.i + 0x7FFFu + ((v.i >> 16) & 1u);
  return (unsigned short)(b >> 16);
}
__device__ __forceinline__ void gload16(const void* g, void* l) {
  __builtin_amdgcn_global_load_lds(
      (const __attribute__((address_space(1))) unsigned int*)g,
      (__attribute__((address_space(3))) unsigned int*)l,
      16, 0, 0);
}
__device__ __forceinline__ float elu1(float v) {
  return v > 0.f ? v + 1.f : __expf(v);
}

// ---------------- kernel P1: pure streaming x -> bf16 (branch-free) ----------------
__global__ __launch_bounds__(256)
void prep_x_kernel(const float* __restrict__ x, unsigned short* __restrict__ xb) {
  const int XN = MROWS * CDIM / 8;         // 2097152 8-elem groups
  for (int j = blockIdx.x * blockDim.x + threadIdx.x; j < XN;
       j += gridDim.x * blockDim.x) {
    const float4* xp = (const float4*)x + (size_t)j * 2;
    const float4 a = xp[0], b4 = xp[1];
    u16x8 o;
    o[0] = f2bf(a.x);  o[1] = f2bf(a.y);  o[2] = f2bf(a.z);  o[3] = f2bf(a.w);
    o[4] = f2bf(b4.x); o[5] = f2bf(b4.y); o[6] = f2bf(b4.z); o[7] = f2bf(b4.w);
    *((u16x8*)xb + j) = o;
  }
}

// ---------------- kernel P2: zero reductions, transpose+convert W, trig LUT, transpose lepe_w ----------------
__global__ void prep_misc_kernel(const float* __restrict__ Wqk, const float* __restrict__ lepe_w,
                                 float* __restrict__ wsf, unsigned short* __restrict__ wT,
                                 float2* __restrict__ trig, float* __restrict__ wt9) {
  const int ZN = (int)(OFF_XB / 4);        // 135168 floats (ksum+kv)
  const int WN = (KDIM * NCOL) / 8;        // 65536
  const int TN = 64 * 128;                 // 8192
  const int W9 = 9 * 512;                  // 4608
  const int total = ZN + WN + TN + W9;
  for (int i = blockIdx.x * blockDim.x + threadIdx.x; i < total;
       i += gridDim.x * blockDim.x) {
    if (i < ZN) {
      wsf[i] = 0.f;
    } else if (i < ZN + WN) {
      const int j = i - ZN;
      const int nc8 = j & 127;     // 8-column group
      const int k   = j >> 7;      // 0..511
      const float4* wp = (const float4*)(Wqk + (size_t)k * NCOL + nc8 * 8);
      const float4 a = wp[0], b4 = wp[1];
      const float vals[8] = {a.x, a.y, a.z, a.w, b4.x, b4.y, b4.z, b4.w};
      const int nc0 = nc8 * 8;
#pragma unroll
      for (int t = 0; t < 8; ++t) wT[(size_t)(nc0 + t) * KDIM + k] = f2bf(vals[t]);
    } else if (i < ZN + WN + TN) {
      const int j = i - ZN - WN;
      const int tt = j & 127;
      const int pos = j >> 7;      // 0..63
      const float theta = __expf(-(float)tt * 0.07195578415f); // ln(1e4)/128
      const float ang = (float)pos * theta;
      float s, c;
      sincosf(ang, &s, &c);
      trig[pos * 128 + tt] = make_float2(c, s);
    } else {
      const int j = i - ZN - WN - TN;
      const int tap = j >> 9;      // 0..8
      const int c   = j & 511;
      wt9[tap * 512 + c] = lepe_w[c * 9 + tap];
    }
  }
}

// ---------------- kernel A: bf16 MFMA GEMM — 256^2, 8 waves, 2-quadrant phases, 3-buf counted-vmcnt,
// slot-swizzled LDS (slot ^= (row>>1)&3): conflict-free ds_read_b128, coalescing-preserving source perm ----------------
__global__ __launch_bounds__(512)
void gemm_kernel(const unsigned short* __restrict__ xb, const unsigned short* __restrict__ wT,
                 const float* __restrict__ bqk, const float2* __restrict__ trig,
                 unsigned short* __restrict__ qp, unsigned short* __restrict__ kr,
                 float* __restrict__ ksum) {
  __shared__ __align__(16) unsigned short S[3][2][8192];   // 3 bufs x (A,B) x 256x32 bf16 = 96 KB
  float* Cst = (float*)&S[0][0][0];                        // epilogue alias (33.3 KB)
  const int tid = threadIdx.x;
  const int wid = tid >> 6;
  const int l = tid & 63;
  const int la = l & 15, lg = l >> 4;
  const int wm = wid >> 2, wn = wid & 3;   // 2 m-waves x 4 n-waves
  const int nt = blockIdx.x;               // 0..3 (0,1 = q cols; 2,3 = k cols)
  const int m0 = blockIdx.y * 256;
  const int n0 = nt * 256;

  f32x4 acc[8][4];
#pragma unroll
  for (int i = 0; i < 8; ++i)
#pragma unroll
    for (int j = 0; j < 4; ++j) acc[i][j] = (f32x4){0.f, 0.f, 0.f, 0.f};

  const int srow = tid >> 2;                             // staging row 0..127
  const int scol = ((tid & 3) ^ ((tid >> 3) & 3)) * 8;   // swizzled k-chunk (same 64B row -> coalescing intact)
  const int rsw = (la >> 1) & 3;                          // read-side slot xor
  const int rslot = (lg ^ rsw) * 8;

#define STG_A(kt, bb, rr) gload16(xb + (size_t)(m0 + (rr) * 128 + srow) * KDIM + (kt) * 32 + scol, \
                                  &S[bb][0][(rr) * 4096 + tid * 8])
#define STG_B(kt, bb, rr) gload16(wT + (size_t)(n0 + (rr) * 128 + srow) * KDIM + (kt) * 32 + scol, \
                                  &S[bb][1][(rr) * 4096 + tid * 8])

  // prologue: tiles 0,1 in flight (8 loads); wait tile 0 (keep tile 1's 4 outstanding)
  STG_A(0, 0, 0); STG_A(0, 0, 1); STG_B(0, 0, 0); STG_B(0, 0, 1);
  STG_A(1, 1, 0); STG_A(1, 1, 1); STG_B(1, 1, 0); STG_B(1, 1, 1);
  asm volatile("s_waitcnt vmcnt(4)" ::: "memory");
  __builtin_amdgcn_s_barrier();
  __builtin_amdgcn_sched_barrier(0);

  for (int kt = 0; kt < 16; ++kt) {
    const int cur = kt % 3;
    const int nx2 = (kt + 2) % 3;
    bf16x8 af[4], bf[4];
    // ---- phase 0: quadrant m0-3 (16 MFMA) ----
#pragma unroll
    for (int i = 0; i < 4; ++i)
      af[i] = *(const bf16x8*)&S[cur][0][(wm * 128 + i * 16 + la) * 32 + rslot];
#pragma unroll
    for (int j = 0; j < 4; ++j)
      bf[j] = *(const bf16x8*)&S[cur][1][(wn * 64 + j * 16 + la) * 32 + rslot];
    if (kt + 2 < 16) { STG_A(kt + 2, nx2, 0); STG_A(kt + 2, nx2, 1); }
    __builtin_amdgcn_s_barrier();
    asm volatile("s_waitcnt lgkmcnt(0)" ::: "memory");
    __builtin_amdgcn_sched_barrier(0);
    __builtin_amdgcn_s_setprio(1);
#pragma unroll
    for (int i = 0; i < 4; ++i)
#pragma unroll
      for (int j = 0; j < 4; ++j)
        acc[i][j] = __builtin_amdgcn_mfma_f32_16x16x32_bf16(af[i], bf[j], acc[i][j], 0, 0, 0);
    __builtin_amdgcn_s_setprio(0);
    __builtin_amdgcn_s_barrier();
    // ---- phase 1: quadrant m4-7 (16 MFMA, reuse bf) ----
#pragma unroll
    for (int i = 0; i < 4; ++i)
      af[i] = *(const bf16x8*)&S[cur][0][(wm * 128 + (4 + i) * 16 + la) * 32 + rslot];
    if (kt + 2 < 16) { STG_B(kt + 2, nx2, 0); STG_B(kt + 2, nx2, 1); }
    __builtin_amdgcn_s_barrier();
    asm volatile("s_waitcnt lgkmcnt(0)" ::: "memory");
    __builtin_amdgcn_sched_barrier(0);
    __builtin_amdgcn_s_setprio(1);
#pragma unroll
    for (int i = 0; i < 4; ++i)
#pragma unroll
      for (int j = 0; j < 4; ++j)
        acc[4 + i][j] = __builtin_amdgcn_mfma_f32_16x16x32_bf16(af[i], bf[j], acc[4 + i][j], 0, 0, 0);
    __builtin_amdgcn_s_setprio(0);
    // end of K-tile: retire kt+1's 4 loads, keep kt+2's 4 in flight (never vmcnt(0) mid-loop)
    if (kt < 14) {
      asm volatile("s_waitcnt vmcnt(4)" ::: "memory");
    } else if (kt == 14) {
      asm volatile("s_waitcnt vmcnt(0)" ::: "memory");
    }
    __builtin_amdgcn_s_barrier();
    __builtin_amdgcn_sched_barrier(0);
  }
#undef STG_A
#undef STG_B

  // ---- epilogue phase 1: bias + elu in acc layout; k colsum -> ksum atomics ----
  const bool isq = (nt < 2);
  const int bidx = m0 >> 12;   // batch (block-uniform; 256-row tile within one batch)
  float colsum[4] = {0.f, 0.f, 0.f, 0.f};
#pragma unroll
  for (int j = 0; j < 4; ++j) {
    const float bias = bqk[n0 + wn * 64 + j * 16 + la];
#pragma unroll
    for (int i = 0; i < 8; ++i) {
#pragma unroll
      for (int r = 0; r < 4; ++r) {
        const float v = elu1(acc[i][j][r] + bias);
        acc[i][j][r] = v;
        if (!isq) colsum[j] += v;
      }
    }
  }
  if (!isq) {
#pragma unroll
    for (int j = 0; j < 4; ++j) {
      float s = colsum[j];
      s += __shfl_xor(s, 16);
      s += __shfl_xor(s, 32);
      if (lg == 0) {
        atomicAdd(&ksum[bidx * CDIM + (n0 - 512) + wn * 64 + j * 16 + la], s);
      }
    }
  }

  // ---- epilogue phase 2: LDS restage (8 chunks of 32 rows x 256 cols), coalesced bf16x8 stores ----
  for (int cc = 0; cc < 8; ++cc) {
    __syncthreads();
    if (wm == (cc >> 2)) {
      const int mi0 = (cc & 3) * 2;
#pragma unroll
      for (int mil = 0; mil < 2; ++mil) {
#pragma unroll
        for (int j = 0; j < 4; ++j) {
#pragma unroll
          for (int r = 0; r < 4; ++r) {
            Cst[(mil * 16 + lg * 4 + r) * 260 + wn * 64 + j * 16 + la] = acc[mi0 + mil][j][r];
          }
        }
      }
    }
    __syncthreads();
#pragma unroll
    for (int it = 0; it < 2; ++it) {
      const int idx = it * 512 + tid;
      const int rowloc = idx >> 5;       // 0..31
      const int seg = idx & 31;          // 8-f32 segment (256 cols)
      const int grow = m0 + cc * 32 + rowloc;
      const int lcol = seg * 8;
      float v[8];
      *(float2*)&v[0] = *(const float2*)&Cst[rowloc * 260 + lcol + 0];
      *(float2*)&v[2] = *(const float2*)&Cst[rowloc * 260 + lcol + 2];
      *(float2*)&v[4] = *(const float2*)&Cst[rowloc * 260 + lcol + 4];
      *(float2*)&v[6] = *(const float2*)&Cst[rowloc * 260 + lcol + 6];
      if (isq) {
        u16x8 o;
#pragma unroll
        for (int jj = 0; jj < 8; ++jj) o[jj] = f2bf(v[jj]);
        *(u16x8*)(qp + (size_t)grow * CDIM + n0 + lcol) = o;
      } else {
        const int ck0 = (n0 - 512) + lcol;
        const int n = grow & (NTOK - 1);
        const int p0 = ck0 >> 1;                       // 4 pairs p0..p0+3 (p0 % 4 == 0)
        const int pos = (p0 >= 128) ? (n & 63) : (n >> 6);
        const float4 t01 = *(const float4*)&trig[pos * 128 + (p0 & 127)];
        const float4 t23 = *(const float4*)&trig[pos * 128 + (p0 & 127) + 2];
        u16x8 o;
        o[0] = f2bf(v[0] * t01.x - v[1] * t01.y);
        o[1] = f2bf(v[1] * t01.x + v[0] * t01.y);
        o[2] = f2bf(v[2] * t01.z - v[3] * t01.w);
        o[3] = f2bf(v[3] * t01.z + v[2] * t01.w);
        o[4] = f2bf(v[4] * t23.x - v[5] * t23.y);
        o[5] = f2bf(v[5] * t23.x + v[4] * t23.y);
        o[6] = f2bf(v[6] * t23.z - v[7] * t23.w);
        o[7] = f2bf(v[7] * t23.z + v[6] * t23.w);
        *(u16x8*)(kr + (size_t)grow * CDIM + ck0) = o;
      }
    }
  }
}

// ---------------- kernel B: kv partials — LDS-staged coalesced, 3-buf counted-vmcnt, direct atomics ----------------
// 256 blocks = (b, 32 chunks of 128 rows), 256 threads = (16 h, 8x8 d/e subtile).
// Accumulates in registers; atomicAdd into L2-resident kv (zeroed by prep_misc). No kvred pass.
__global__ __launch_bounds__(256)
void kvpart_kernel(const unsigned short* __restrict__ kr, const unsigned short* __restrict__ xb,
                   float* __restrict__ kv) {
  __shared__ __align__(16) unsigned short kbuf[3][8 * 512];   // 3 x 8 KB
  __shared__ __align__(16) unsigned short vbuf[3][8 * 512];   // 3 x 8 KB (48 KB total)
  const int bid = blockIdx.x;
  const int b = bid >> 5, ch = bid & 31;
  const int t = threadIdx.x;
  const int h = t >> 4;
  const int sub = t & 15;
  const int d0 = (sub >> 2) * 8, e0 = (sub & 3) * 8;
  const int srow = t >> 6;          // wave-uniform row offset 0..3
  const int scol = (t & 63) * 8;    // lane element offset (16B/lane, coalesced)
  const size_t base = (size_t)(b * NTOK + ch * 128) * CDIM;

  float acc[8][8];
#pragma unroll
  for (int i = 0; i < 8; ++i)
#pragma unroll
    for (int j = 0; j < 8; ++j) acc[i][j] = 0.f;

  // stage tile tt (8 rows x 512 ch of kr and xb) into buf bb: 4 gload16/thread
#define KVSTG(tt, bb) do {                                                                  \
    gload16(kr + base + (size_t)((tt) * 8 + srow) * CDIM + scol,     &kbuf[bb][srow * 512 + scol]);       \
    gload16(kr + base + (size_t)((tt) * 8 + 4 + srow) * CDIM + scol, &kbuf[bb][(4 + srow) * 512 + scol]); \
    gload16(xb + base + (size_t)((tt) * 8 + srow) * CDIM + scol,     &vbuf[bb][srow * 512 + scol]);       \
    gload16(xb + base + (size_t)((tt) * 8 + 4 + srow) * CDIM + scol, &vbuf[bb][(4 + srow) * 512 + scol]); \
  } while (0)

  KVSTG(0, 0);
  for (int tt = 0; tt < 16; ++tt) {
    const int cb = tt % 3;
    if (tt < 15) {
      KVSTG(tt + 1, (tt + 1) % 3);
      asm volatile("s_waitcnt vmcnt(4)" ::: "memory");  // retire tile tt's 4 loads
    } else {
      asm volatile("s_waitcnt vmcnt(0)" ::: "memory");
    }
    __builtin_amdgcn_s_barrier();
#pragma unroll
    for (int r = 0; r < 8; ++r) {
      const u16x8 k8 = *(const u16x8*)&kbuf[cb][r * 512 + h * 32 + d0];
      const u16x8 v8 = *(const u16x8*)&vbuf[cb][r * 512 + h * 32 + e0];
      float kf[8], vf[8];
#pragma unroll
      for (int i = 0; i < 8; ++i) { kf[i] = bf2f(k8[i]); vf[i] = bf2f(v8[i]); }
#pragma unroll
      for (int i = 0; i < 8; ++i)
#pragma unroll
        for (int j = 0; j < 8; ++j) acc[i][j] += kf[i] * vf[j];
    }
    __builtin_amdgcn_s_barrier();   // all waves done reading cb before it is restaged
  }
#undef KVSTG

  // accumulate directly into kv[b][h][32][32] (L2-resident, 32 adds/location total)
  const float inv_n = 1.0f / (float)NTOK;
  float* p = kv + ((size_t)(b * 16 + h)) * 1024;
#pragma unroll
  for (int i = 0; i < 8; ++i)
#pragma unroll
    for (int j = 0; j < 8; ++j)
      atomicAdd(&p[(d0 + i) * 32 + e0 + j], acc[i][j] * inv_n);
}

// ---------------- kernel C: out5 — 8 ch/thread, one pass, LDS-staged constants ----------------
// grid (64 y, 16 h, 8 b), 256 threads = 64 cols x 4 lanes of 8 ch.
__global__ __launch_bounds__(256)
void out5_kernel(const unsigned short* __restrict__ qp, const float* __restrict__ ksum,
                 const float* __restrict__ kv, const float2* __restrict__ trig,
                 const unsigned short* __restrict__ xb, const float* __restrict__ wt9,
                 const float* __restrict__ lepe_b, float* __restrict__ out) {
  __shared__ __align__(16) float kvs[32 * 32];   // [d][e] 4 KB
  __shared__ __align__(16) float qrs[64 * 36];   // [col][36] padded, same-wave exchange (9.2 KB)
  __shared__ __align__(16) float wls[9 * 32];    // conv weights this head
  __shared__ __align__(16) float ksl[32];        // k_mean this (b,h)
  __shared__ __align__(16) float lbl[32];        // lepe bias this head
  const int y = blockIdx.x, h = blockIdx.y, b = blockIdx.z;
  const int t = threadIdx.x;
  const int col = t >> 2, e4 = t & 3;
  const int c8 = e4 * 8;

  // stage kv tile (coalesced float4)
  ((float4*)kvs)[t] = ((const float4*)(kv + (size_t)(b * 16 + h) * 1024))[t];
  if (t < 72) {
    ((float4*)wls)[t] = *(const float4*)(wt9 + (t >> 3) * CDIM + h * 32 + (t & 7) * 4);
  } else if (t < 80) {
    ((float4*)ksl)[t - 72] = *(const float4*)(ksum + b * CDIM + h * 32 + (t - 72) * 4);
  } else if (t < 88) {
    ((float4*)lbl)[t - 80] = *(const float4*)(lepe_b + h * 32 + (t - 80) * 4);
  }
  __syncthreads();

  const float inv_n = 1.0f / (float)NTOK;
  const int n = y * 64 + col;
  const size_t rowoff = ((size_t)(b * NTOK + n)) * CDIM + h * 32;

  // q plain (8 ch, one 16B load)
  const u16x8 q8 = *(const u16x8*)(qp + rowoff + c8);
  float qf[8];
#pragma unroll
  for (int i = 0; i < 8; ++i) qf[i] = bf2f(q8[i]);
  // z: partial over 8 ch, reduce over 4 lanes of this token
  float zs = 0.f;
#pragma unroll
  for (int i = 0; i < 8; ++i) zs += qf[i] * ksl[c8 + i];
  zs += __shfl_xor(zs, 1);
  zs += __shfl_xor(zs, 2);
  const float z = 1.0f / (zs * inv_n + 1e-6f);
  // q rope: 4 pairs, all within this thread's 8 channels
  const int pbase = (h * 16 + e4 * 4) & 127;
  const int pos = (h >= 8) ? col : y;
  const float4 csA = *(const float4*)&trig[pos * 128 + pbase];
  const float4 csB = *(const float4*)&trig[pos * 128 + pbase + 2];
  float qr[8];
  qr[0] = qf[0] * csA.x - qf[1] * csA.y;
  qr[1] = qf[1] * csA.x + qf[0] * csA.y;
  qr[2] = qf[2] * csA.z - qf[3] * csA.w;
  qr[3] = qf[3] * csA.z + qf[2] * csA.w;
  qr[4] = qf[4] * csB.x - qf[5] * csB.y;
  qr[5] = qf[5] * csB.x + qf[4] * csB.y;
  qr[6] = qf[6] * csB.z - qf[7] * csB.w;
  qr[7] = qf[7] * csB.z + qf[6] * csB.w;
  *(float4*)&qrs[col * 36 + c8] = *(float4*)&qr[0];       // same-wave exchange, no barrier
  *(float4*)&qrs[col * 36 + c8 + 4] = *(float4*)&qr[4];
  // LePE 3x3 conv (16B taps from bf16 xb; weights from LDS)
  float accv[8];
#pragma unroll
  for (int i = 0; i < 8; ++i) accv[i] = lbl[c8 + i];
#pragma unroll
  for (int dy = 0; dy < 3; ++dy) {
    const int iy = y + dy - 1;
    if (iy < 0 || iy > 63) continue;
#pragma unroll
    for (int dx = 0; dx < 3; ++dx) {
      const int ix = col + dx - 1;
      if (ix < 0 || ix > 63) continue;
      const u16x8 xv = *(const u16x8*)(xb + ((size_t)(b * NTOK) + iy * 64 + ix) * CDIM + h * 32 + c8);
      const float* wrow = &wls[(dy * 3 + dx) * 32 + c8];
#pragma unroll
      for (int i = 0; i < 8; ++i) accv[i] += bf2f(xv[i]) * wrow[i];
    }
  }
  // attn[e] = sum_d qr[d]*kv[d][e] (qr for this token from LDS, kv rows b128)
  float attn[8] = {0.f, 0.f, 0.f, 0.f, 0.f, 0.f, 0.f, 0.f};
#pragma unroll
  for (int dg = 0; dg < 8; ++dg) {
    const float4 qv = *(const float4*)&qrs[col * 36 + dg * 4];
#pragma unroll
    for (int j = 0; j < 4; ++j) {
      const float qs = (j == 0) ? qv.x : (j == 1) ? qv.y : (j == 2) ? qv.z : qv.w;
      const float4 kv0 = *(const float4*)&kvs[(dg * 4 + j) * 32 + c8];
      const float4 kv1 = *(const float4*)&kvs[(dg * 4 + j) * 32 + c8 + 4];
      attn[0] += qs * kv0.x; attn[1] += qs * kv0.y; attn[2] += qs * kv0.z; attn[3] += qs * kv0.w;
      attn[4] += qs * kv1.x; attn[5] += qs * kv1.y; attn[6] += qs * kv1.z; attn[7] += qs * kv1.w;
    }
  }
  float4 r0, r1;
  r0.x = attn[0] * z + accv[0]; r0.y = attn[1] * z + accv[1];
  r0.z = attn[2] * z + accv[2]; r0.w = attn[3] * z + accv[3];
  r1.x = attn[4] * z + accv[4]; r1.y = attn[5] * z + accv[5];
  r1.z = attn[6] * z + accv[6]; r1.w = attn[7] * z + accv[7];
  *(float4*)(out + rowoff + c8) = r0;
  *(float4*)(out + rowoff + c8 + 4) = r1;
}

// ---------------- launch ----------------
extern "C" void kernel_launch(void* const* d_in, const int* in_sizes, int n_in,
                              void* d_out, int out_size, void* d_ws, size_t ws_size,
                              hipStream_t stream) {
  const float* x      = (const float*)d_in[0];
  // d_in[1]=h, d_in[2]=w (ints, fixed 64 — hardcoded)
  const float* Wqk    = (const float*)d_in[3];
  const float* bqk    = (const float*)d_in[4];
  const float* lepe_w = (const float*)d_in[5];
  const float* lepe_b = (const float*)d_in[6];
  float* out = (float*)d_out;

  if (ws_size < WS_NEED) return;

  char* ws = (char*)d_ws;
  float* ksum            = (float*)(ws + OFF_KSUM);
  float* kv              = (float*)(ws + OFF_KV);
  unsigned short* xb     = (unsigned short*)(ws + OFF_XB);
  unsigned short* wT     = (unsigned short*)(ws + OFF_WT);
  unsigned short* qp     = (unsigned short*)(ws + OFF_QP);
  unsigned short* kr     = (unsigned short*)(ws + OFF_KR);
  float2* trig           = (float2*)(ws + OFF_TRIG);
  float* wt9             = (float*)(ws + OFF_WT9);

  hipLaunchKernelGGL(prep_x_kernel, dim3(2048), dim3(256), 0, stream, x, xb);
  hipLaunchKernelGGL(prep_misc_kernel, dim3(256), dim3(256), 0, stream,
                     Wqk, lepe_w, (float*)ws, wT, trig, wt9);
  hipLaunchKernelGGL(gemm_kernel, dim3(4, MROWS / 256), dim3(512), 0, stream,
                     xb, wT, bqk, trig, qp, kr, ksum);
  hipLaunchKernelGGL(kvpart_kernel, dim3(BATCH * KV_CHUNKS), dim3(256), 0, stream,
                     kr, xb, kv);
  hipLaunchKernelGGL(out5_kernel, dim3(64, 16, 8), dim3(256), 0, stream,
                     qp, ksum, kv, trig, xb, wt9, lepe_b, out);
}

// Round 21
// 158.988 us; speedup vs baseline: 1.6827x; 1.6827x over previous
//
#include <hip/hip_runtime.h>
#include <stdint.h>

// ---------------- problem constants (fixed by harness) ----------------
static constexpr int BATCH = 8;
static constexpr int NTOK  = 4096;          // 64*64
static constexpr int CDIM  = 512;
static constexpr int NCOL  = 1024;          // 2C
static constexpr int MROWS = BATCH * NTOK;  // 32768
static constexpr int KDIM  = 512;

// ---------------- workspace layout ----------------
static constexpr size_t OFF_KSUM = 0;                         // 8*512 f32        = 16384 B
static constexpr size_t OFF_KV   = 16384;                     // 8*16*32*32 f32   = 524288 B
static constexpr size_t OFF_XB   = 540672;                    // bf16 x           = 33554432 B
static constexpr size_t OFF_WT   = OFF_XB + 33554432;         // bf16 W^T         = 1048576 B
static constexpr size_t OFF_QP   = OFF_WT + 1048576;          // bf16 q_plain     = 33554432 B
static constexpr size_t OFF_KR   = OFF_QP + 33554432;         // bf16 k_rope      = 33554432 B
static constexpr size_t OFF_TRIG = OFF_KR + 33554432;         // 64*128 float2    = 65536 B
static constexpr size_t OFF_WT9  = OFF_TRIG + 65536;          // 9*512 f32        = 18432 B
static constexpr size_t WS_NEED  = OFF_WT9 + 18432;           // ~102.4 MB

// kv two-stage constants (32 chunks of 128 rows — 16.8 MB partials)
static constexpr int KV_CHUNKS = 32;
static constexpr int KV_OUT    = BATCH * 16 * 32 * 32;        // 131072 outputs

// ---------------- helpers ----------------
typedef __attribute__((ext_vector_type(8))) short bf16x8;
typedef __attribute__((ext_vector_type(4))) float f32x4;
typedef __attribute__((ext_vector_type(8))) unsigned short u16x8;

__device__ __forceinline__ float bf2f(unsigned short u) {
  union { unsigned int i; float f; } v; v.i = ((unsigned int)u) << 16; return v.f;
}
__device__ __forceinline__ unsigned short f2bf(float f) {
  union { float f; unsigned int i; } v; v.f = f;
  unsigned int b = v.i + 0x7FFFu + ((v.i >> 16) & 1u);
  return (unsigned short)(b >> 16);
}
__device__ __forceinline__ void gload16(const void* g, void* l) {
  __builtin_amdgcn_global_load_lds(
      (const __attribute__((address_space(1))) unsigned int*)g,
      (__attribute__((address_space(3))) unsigned int*)l,
      16, 0, 0);
}
__device__ __forceinline__ float elu1(float v) {
  return v > 0.f ? v + 1.f : __expf(v);
}

// ---------------- kernel P1: pure streaming x -> bf16 (branch-free) ----------------
__global__ __launch_bounds__(256)
void prep_x_kernel(const float* __restrict__ x, unsigned short* __restrict__ xb) {
  const int XN = MROWS * CDIM / 8;         // 2097152 8-elem groups
  for (int j = blockIdx.x * blockDim.x + threadIdx.x; j < XN;
       j += gridDim.x * blockDim.x) {
    const float4* xp = (const float4*)x + (size_t)j * 2;
    const float4 a = xp[0], b4 = xp[1];
    u16x8 o;
    o[0] = f2bf(a.x);  o[1] = f2bf(a.y);  o[2] = f2bf(a.z);  o[3] = f2bf(a.w);
    o[4] = f2bf(b4.x); o[5] = f2bf(b4.y); o[6] = f2bf(b4.z); o[7] = f2bf(b4.w);
    *((u16x8*)xb + j) = o;
  }
}

// ---------------- kernel P2: zero reductions, transpose+convert W, trig LUT, transpose lepe_w ----------------
__global__ void prep_misc_kernel(const float* __restrict__ Wqk, const float* __restrict__ lepe_w,
                                 float* __restrict__ wsf, unsigned short* __restrict__ wT,
                                 float2* __restrict__ trig, float* __restrict__ wt9) {
  const int ZN = (int)(OFF_XB / 4);        // 135168 floats (ksum+kv)
  const int WN = (KDIM * NCOL) / 8;        // 65536
  const int TN = 64 * 128;                 // 8192
  const int W9 = 9 * 512;                  // 4608
  const int total = ZN + WN + TN + W9;
  for (int i = blockIdx.x * blockDim.x + threadIdx.x; i < total;
       i += gridDim.x * blockDim.x) {
    if (i < ZN) {
      wsf[i] = 0.f;
    } else if (i < ZN + WN) {
      const int j = i - ZN;
      const int nc8 = j & 127;     // 8-column group
      const int k   = j >> 7;      // 0..511
      const float4* wp = (const float4*)(Wqk + (size_t)k * NCOL + nc8 * 8);
      const float4 a = wp[0], b4 = wp[1];
      const float vals[8] = {a.x, a.y, a.z, a.w, b4.x, b4.y, b4.z, b4.w};
      const int nc0 = nc8 * 8;
#pragma unroll
      for (int t = 0; t < 8; ++t) wT[(size_t)(nc0 + t) * KDIM + k] = f2bf(vals[t]);
    } else if (i < ZN + WN + TN) {
      const int j = i - ZN - WN;
      const int tt = j & 127;
      const int pos = j >> 7;      // 0..63
      const float theta = __expf(-(float)tt * 0.07195578415f); // ln(1e4)/128
      const float ang = (float)pos * theta;
      float s, c;
      sincosf(ang, &s, &c);
      trig[pos * 128 + tt] = make_float2(c, s);
    } else {
      const int j = i - ZN - WN - TN;
      const int tap = j >> 9;      // 0..8
      const int c   = j & 511;
      wt9[tap * 512 + c] = lepe_w[c * 9 + tap];
    }
  }
}

// ---------------- kernel A: bf16 MFMA GEMM — 256^2, 8 waves, 2-quadrant phases, 3-buf counted-vmcnt,
// slot-swizzled LDS (slot ^= (row>>1)&3): conflict-free ds_read_b128, coalescing-preserving source perm ----------------
__global__ __launch_bounds__(512)
void gemm_kernel(const unsigned short* __restrict__ xb, const unsigned short* __restrict__ wT,
                 const float* __restrict__ bqk, const float2* __restrict__ trig,
                 unsigned short* __restrict__ qp, unsigned short* __restrict__ kr,
                 float* __restrict__ ksum) {
  __shared__ __align__(16) unsigned short S[3][2][8192];   // 3 bufs x (A,B) x 256x32 bf16 = 96 KB
  float* Cst = (float*)&S[0][0][0];                        // epilogue alias (33.3 KB)
  const int tid = threadIdx.x;
  const int wid = tid >> 6;
  const int l = tid & 63;
  const int la = l & 15, lg = l >> 4;
  const int wm = wid >> 2, wn = wid & 3;   // 2 m-waves x 4 n-waves
  const int nt = blockIdx.x;               // 0..3 (0,1 = q cols; 2,3 = k cols)
  const int m0 = blockIdx.y * 256;
  const int n0 = nt * 256;

  f32x4 acc[8][4];
#pragma unroll
  for (int i = 0; i < 8; ++i)
#pragma unroll
    for (int j = 0; j < 4; ++j) acc[i][j] = (f32x4){0.f, 0.f, 0.f, 0.f};

  const int srow = tid >> 2;                             // staging row 0..127
  const int scol = ((tid & 3) ^ ((tid >> 3) & 3)) * 8;   // swizzled k-chunk (same 64B row -> coalescing intact)
  const int rsw = (la >> 1) & 3;                          // read-side slot xor
  const int rslot = (lg ^ rsw) * 8;

#define STG_A(kt, bb, rr) gload16(xb + (size_t)(m0 + (rr) * 128 + srow) * KDIM + (kt) * 32 + scol, \
                                  &S[bb][0][(rr) * 4096 + tid * 8])
#define STG_B(kt, bb, rr) gload16(wT + (size_t)(n0 + (rr) * 128 + srow) * KDIM + (kt) * 32 + scol, \
                                  &S[bb][1][(rr) * 4096 + tid * 8])

  // prologue: tiles 0,1 in flight (8 loads); wait tile 0 (keep tile 1's 4 outstanding)
  STG_A(0, 0, 0); STG_A(0, 0, 1); STG_B(0, 0, 0); STG_B(0, 0, 1);
  STG_A(1, 1, 0); STG_A(1, 1, 1); STG_B(1, 1, 0); STG_B(1, 1, 1);
  asm volatile("s_waitcnt vmcnt(4)" ::: "memory");
  __builtin_amdgcn_s_barrier();
  __builtin_amdgcn_sched_barrier(0);

  for (int kt = 0; kt < 16; ++kt) {
    const int cur = kt % 3;
    const int nx2 = (kt + 2) % 3;
    bf16x8 af[4], bf[4];
    // ---- phase 0: quadrant m0-3 (16 MFMA) ----
#pragma unroll
    for (int i = 0; i < 4; ++i)
      af[i] = *(const bf16x8*)&S[cur][0][(wm * 128 + i * 16 + la) * 32 + rslot];
#pragma unroll
    for (int j = 0; j < 4; ++j)
      bf[j] = *(const bf16x8*)&S[cur][1][(wn * 64 + j * 16 + la) * 32 + rslot];
    if (kt + 2 < 16) { STG_A(kt + 2, nx2, 0); STG_A(kt + 2, nx2, 1); }
    __builtin_amdgcn_s_barrier();
    asm volatile("s_waitcnt lgkmcnt(0)" ::: "memory");
    __builtin_amdgcn_sched_barrier(0);
    __builtin_amdgcn_s_setprio(1);
#pragma unroll
    for (int i = 0; i < 4; ++i)
#pragma unroll
      for (int j = 0; j < 4; ++j)
        acc[i][j] = __builtin_amdgcn_mfma_f32_16x16x32_bf16(af[i], bf[j], acc[i][j], 0, 0, 0);
    __builtin_amdgcn_s_setprio(0);
    __builtin_amdgcn_s_barrier();
    // ---- phase 1: quadrant m4-7 (16 MFMA, reuse bf) ----
#pragma unroll
    for (int i = 0; i < 4; ++i)
      af[i] = *(const bf16x8*)&S[cur][0][(wm * 128 + (4 + i) * 16 + la) * 32 + rslot];
    if (kt + 2 < 16) { STG_B(kt + 2, nx2, 0); STG_B(kt + 2, nx2, 1); }
    __builtin_amdgcn_s_barrier();
    asm volatile("s_waitcnt lgkmcnt(0)" ::: "memory");
    __builtin_amdgcn_sched_barrier(0);
    __builtin_amdgcn_s_setprio(1);
#pragma unroll
    for (int i = 0; i < 4; ++i)
#pragma unroll
      for (int j = 0; j < 4; ++j)
        acc[4 + i][j] = __builtin_amdgcn_mfma_f32_16x16x32_bf16(af[i], bf[j], acc[4 + i][j], 0, 0, 0);
    __builtin_amdgcn_s_setprio(0);
    // end of K-tile: retire kt+1's 4 loads, keep kt+2's 4 in flight (never vmcnt(0) mid-loop)
    if (kt < 14) {
      asm volatile("s_waitcnt vmcnt(4)" ::: "memory");
    } else if (kt == 14) {
      asm volatile("s_waitcnt vmcnt(0)" ::: "memory");
    }
    __builtin_amdgcn_s_barrier();
    __builtin_amdgcn_sched_barrier(0);
  }
#undef STG_A
#undef STG_B

  // ---- epilogue phase 1: bias + elu in acc layout; k colsum -> ksum atomics ----
  const bool isq = (nt < 2);
  const int bidx = m0 >> 12;   // batch (block-uniform; 256-row tile within one batch)
  float colsum[4] = {0.f, 0.f, 0.f, 0.f};
#pragma unroll
  for (int j = 0; j < 4; ++j) {
    const float bias = bqk[n0 + wn * 64 + j * 16 + la];
#pragma unroll
    for (int i = 0; i < 8; ++i) {
#pragma unroll
      for (int r = 0; r < 4; ++r) {
        const float v = elu1(acc[i][j][r] + bias);
        acc[i][j][r] = v;
        if (!isq) colsum[j] += v;
      }
    }
  }
  if (!isq) {
#pragma unroll
    for (int j = 0; j < 4; ++j) {
      float s = colsum[j];
      s += __shfl_xor(s, 16);
      s += __shfl_xor(s, 32);
      if (lg == 0) {
        atomicAdd(&ksum[bidx * CDIM + (n0 - 512) + wn * 64 + j * 16 + la], s);
      }
    }
  }

  // ---- epilogue phase 2: LDS restage (8 chunks of 32 rows x 256 cols), coalesced bf16x8 stores ----
  for (int cc = 0; cc < 8; ++cc) {
    __syncthreads();
    if (wm == (cc >> 2)) {
      const int mi0 = (cc & 3) * 2;
#pragma unroll
      for (int mil = 0; mil < 2; ++mil) {
#pragma unroll
        for (int j = 0; j < 4; ++j) {
#pragma unroll
          for (int r = 0; r < 4; ++r) {
            Cst[(mil * 16 + lg * 4 + r) * 260 + wn * 64 + j * 16 + la] = acc[mi0 + mil][j][r];
          }
        }
      }
    }
    __syncthreads();
#pragma unroll
    for (int it = 0; it < 2; ++it) {
      const int idx = it * 512 + tid;
      const int rowloc = idx >> 5;       // 0..31
      const int seg = idx & 31;          // 8-f32 segment (256 cols)
      const int grow = m0 + cc * 32 + rowloc;
      const int lcol = seg * 8;
      float v[8];
      *(float2*)&v[0] = *(const float2*)&Cst[rowloc * 260 + lcol + 0];
      *(float2*)&v[2] = *(const float2*)&Cst[rowloc * 260 + lcol + 2];
      *(float2*)&v[4] = *(const float2*)&Cst[rowloc * 260 + lcol + 4];
      *(float2*)&v[6] = *(const float2*)&Cst[rowloc * 260 + lcol + 6];
      if (isq) {
        u16x8 o;
#pragma unroll
        for (int jj = 0; jj < 8; ++jj) o[jj] = f2bf(v[jj]);
        *(u16x8*)(qp + (size_t)grow * CDIM + n0 + lcol) = o;
      } else {
        const int ck0 = (n0 - 512) + lcol;
        const int n = grow & (NTOK - 1);
        const int p0 = ck0 >> 1;                       // 4 pairs p0..p0+3 (p0 % 4 == 0)
        const int pos = (p0 >= 128) ? (n & 63) : (n >> 6);
        const float4 t01 = *(const float4*)&trig[pos * 128 + (p0 & 127)];
        const float4 t23 = *(const float4*)&trig[pos * 128 + (p0 & 127) + 2];
        u16x8 o;
        o[0] = f2bf(v[0] * t01.x - v[1] * t01.y);
        o[1] = f2bf(v[1] * t01.x + v[0] * t01.y);
        o[2] = f2bf(v[2] * t01.z - v[3] * t01.w);
        o[3] = f2bf(v[3] * t01.z + v[2] * t01.w);
        o[4] = f2bf(v[4] * t23.x - v[5] * t23.y);
        o[5] = f2bf(v[5] * t23.x + v[4] * t23.y);
        o[6] = f2bf(v[6] * t23.z - v[7] * t23.w);
        o[7] = f2bf(v[7] * t23.z + v[6] * t23.w);
        *(u16x8*)(kr + (size_t)grow * CDIM + ck0) = o;
      }
    }
  }
}

// ---------------- kernel B1: kv partials — LDS-staged coalesced, 3-buf counted-vmcnt pipeline ----------------
// 256 blocks = (b, 32 chunks of 128 rows), 256 threads = (16 h, 8x8 d/e subtile).
__global__ __launch_bounds__(256)
void kvpart_kernel(const unsigned short* __restrict__ kr, const unsigned short* __restrict__ xb,
                   float* __restrict__ part) {
  __shared__ __align__(16) unsigned short kbuf[3][8 * 512];   // 3 x 8 KB
  __shared__ __align__(16) unsigned short vbuf[3][8 * 512];   // 3 x 8 KB (48 KB total)
  const int bid = blockIdx.x;
  const int b = bid >> 5, ch = bid & 31;
  const int t = threadIdx.x;
  const int h = t >> 4;
  const int sub = t & 15;
  const int d0 = (sub >> 2) * 8, e0 = (sub & 3) * 8;
  const int srow = t >> 6;          // wave-uniform row offset 0..3
  const int scol = (t & 63) * 8;    // lane element offset (16B/lane, coalesced)
  const size_t base = (size_t)(b * NTOK + ch * 128) * CDIM;

  float acc[8][8];
#pragma unroll
  for (int i = 0; i < 8; ++i)
#pragma unroll
    for (int j = 0; j < 8; ++j) acc[i][j] = 0.f;

  // stage tile tt (8 rows x 512 ch of kr and xb) into buf bb: 4 gload16/thread
#define KVSTG(tt, bb) do {                                                                  \
    gload16(kr + base + (size_t)((tt) * 8 + srow) * CDIM + scol,     &kbuf[bb][srow * 512 + scol]);       \
    gload16(kr + base + (size_t)((tt) * 8 + 4 + srow) * CDIM + scol, &kbuf[bb][(4 + srow) * 512 + scol]); \
    gload16(xb + base + (size_t)((tt) * 8 + srow) * CDIM + scol,     &vbuf[bb][srow * 512 + scol]);       \
    gload16(xb + base + (size_t)((tt) * 8 + 4 + srow) * CDIM + scol, &vbuf[bb][(4 + srow) * 512 + scol]); \
  } while (0)

  KVSTG(0, 0);
  for (int tt = 0; tt < 16; ++tt) {
    const int cb = tt % 3;
    if (tt < 15) {
      KVSTG(tt + 1, (tt + 1) % 3);
      asm volatile("s_waitcnt vmcnt(4)" ::: "memory");  // retire tile tt's 4 loads
    } else {
      asm volatile("s_waitcnt vmcnt(0)" ::: "memory");
    }
    __builtin_amdgcn_s_barrier();
#pragma unroll
    for (int r = 0; r < 8; ++r) {
      const u16x8 k8 = *(const u16x8*)&kbuf[cb][r * 512 + h * 32 + d0];
      const u16x8 v8 = *(const u16x8*)&vbuf[cb][r * 512 + h * 32 + e0];
      float kf[8], vf[8];
#pragma unroll
      for (int i = 0; i < 8; ++i) { kf[i] = bf2f(k8[i]); vf[i] = bf2f(v8[i]); }
#pragma unroll
      for (int i = 0; i < 8; ++i)
#pragma unroll
        for (int j = 0; j < 8; ++j) acc[i][j] += kf[i] * vf[j];
    }
    __builtin_amdgcn_s_barrier();   // all waves done reading cb before it is restaged
  }
#undef KVSTG

  // store partial tile: part[ch][b][h][32][32], no atomics
  float* p = part + ((size_t)ch * BATCH * 16 + b * 16 + h) * 1024;
#pragma unroll
  for (int i = 0; i < 8; ++i) {
    *(float4*)&p[(d0 + i) * 32 + e0 + 0] = *(float4*)&acc[i][0];
    *(float4*)&p[(d0 + i) * 32 + e0 + 4] = *(float4*)&acc[i][4];
  }
}

// ---------------- kernel B2: reduce 32 partials -> kv ----------------
__global__ __launch_bounds__(256)
void kvred_kernel(const float* __restrict__ part, float* __restrict__ kv) {
  const int o = blockIdx.x * 256 + threadIdx.x;   // 0..131071
  float s0 = 0.f, s1 = 0.f, s2 = 0.f, s3 = 0.f;
#pragma unroll
  for (int ch = 0; ch < KV_CHUNKS; ch += 4) {
    s0 += part[(size_t)(ch + 0) * KV_OUT + o];
    s1 += part[(size_t)(ch + 1) * KV_OUT + o];
    s2 += part[(size_t)(ch + 2) * KV_OUT + o];
    s3 += part[(size_t)(ch + 3) * KV_OUT + o];
  }
  kv[o] = (s0 + s1 + s2 + s3) * (1.0f / (float)NTOK);
}

// ---------------- kernel C: out5 — 8 ch/thread, one pass, LDS-staged constants ----------------
// grid (64 y, 16 h, 8 b), 256 threads = 64 cols x 4 lanes of 8 ch.
__global__ __launch_bounds__(256)
void out5_kernel(const unsigned short* __restrict__ qp, const float* __restrict__ ksum,
                 const float* __restrict__ kv, const float2* __restrict__ trig,
                 const unsigned short* __restrict__ xb, const float* __restrict__ wt9,
                 const float* __restrict__ lepe_b, float* __restrict__ out) {
  __shared__ __align__(16) float kvs[32 * 32];   // [d][e] 4 KB
  __shared__ __align__(16) float qrs[64 * 36];   // [col][36] padded, same-wave exchange (9.2 KB)
  __shared__ __align__(16) float wls[9 * 32];    // conv weights this head
  __shared__ __align__(16) float ksl[32];        // k_mean this (b,h)
  __shared__ __align__(16) float lbl[32];        // lepe bias this head
  const int y = blockIdx.x, h = blockIdx.y, b = blockIdx.z;
  const int t = threadIdx.x;
  const int col = t >> 2, e4 = t & 3;
  const int c8 = e4 * 8;

  // stage kv tile (coalesced float4)
  ((float4*)kvs)[t] = ((const float4*)(kv + (size_t)(b * 16 + h) * 1024))[t];
  if (t < 72) {
    ((float4*)wls)[t] = *(const float4*)(wt9 + (t >> 3) * CDIM + h * 32 + (t & 7) * 4);
  } else if (t < 80) {
    ((float4*)ksl)[t - 72] = *(const float4*)(ksum + b * CDIM + h * 32 + (t - 72) * 4);
  } else if (t < 88) {
    ((float4*)lbl)[t - 80] = *(const float4*)(lepe_b + h * 32 + (t - 80) * 4);
  }
  __syncthreads();

  const float inv_n = 1.0f / (float)NTOK;
  const int n = y * 64 + col;
  const size_t rowoff = ((size_t)(b * NTOK + n)) * CDIM + h * 32;

  // q plain (8 ch, one 16B load)
  const u16x8 q8 = *(const u16x8*)(qp + rowoff + c8);
  float qf[8];
#pragma unroll
  for (int i = 0; i < 8; ++i) qf[i] = bf2f(q8[i]);
  // z: partial over 8 ch, reduce over 4 lanes of this token
  float zs = 0.f;
#pragma unroll
  for (int i = 0; i < 8; ++i) zs += qf[i] * ksl[c8 + i];
  zs += __shfl_xor(zs, 1);
  zs += __shfl_xor(zs, 2);
  const float z = 1.0f / (zs * inv_n + 1e-6f);
  // q rope: 4 pairs, all within this thread's 8 channels
  const int pbase = (h * 16 + e4 * 4) & 127;
  const int pos = (h >= 8) ? col : y;
  const float4 csA = *(const float4*)&trig[pos * 128 + pbase];
  const float4 csB = *(const float4*)&trig[pos * 128 + pbase + 2];
  float qr[8];
  qr[0] = qf[0] * csA.x - qf[1] * csA.y;
  qr[1] = qf[1] * csA.x + qf[0] * csA.y;
  qr[2] = qf[2] * csA.z - qf[3] * csA.w;
  qr[3] = qf[3] * csA.z + qf[2] * csA.w;
  qr[4] = qf[4] * csB.x - qf[5] * csB.y;
  qr[5] = qf[5] * csB.x + qf[4] * csB.y;
  qr[6] = qf[6] * csB.z - qf[7] * csB.w;
  qr[7] = qf[7] * csB.z + qf[6] * csB.w;
  *(float4*)&qrs[col * 36 + c8] = *(float4*)&qr[0];       // same-wave exchange, no barrier
  *(float4*)&qrs[col * 36 + c8 + 4] = *(float4*)&qr[4];
  // LePE 3x3 conv (16B taps from bf16 xb; weights from LDS)
  float accv[8];
#pragma unroll
  for (int i = 0; i < 8; ++i) accv[i] = lbl[c8 + i];
#pragma unroll
  for (int dy = 0; dy < 3; ++dy) {
    const int iy = y + dy - 1;
    if (iy < 0 || iy > 63) continue;
#pragma unroll
    for (int dx = 0; dx < 3; ++dx) {
      const int ix = col + dx - 1;
      if (ix < 0 || ix > 63) continue;
      const u16x8 xv = *(const u16x8*)(xb + ((size_t)(b * NTOK) + iy * 64 + ix) * CDIM + h * 32 + c8);
      const float* wrow = &wls[(dy * 3 + dx) * 32 + c8];
#pragma unroll
      for (int i = 0; i < 8; ++i) accv[i] += bf2f(xv[i]) * wrow[i];
    }
  }
  // attn[e] = sum_d qr[d]*kv[d][e] (qr for this token from LDS, kv rows b128)
  float attn[8] = {0.f, 0.f, 0.f, 0.f, 0.f, 0.f, 0.f, 0.f};
#pragma unroll
  for (int dg = 0; dg < 8; ++dg) {
    const float4 qv = *(const float4*)&qrs[col * 36 + dg * 4];
#pragma unroll
    for (int j = 0; j < 4; ++j) {
      const float qs = (j == 0) ? qv.x : (j == 1) ? qv.y : (j == 2) ? qv.z : qv.w;
      const float4 kv0 = *(const float4*)&kvs[(dg * 4 + j) * 32 + c8];
      const float4 kv1 = *(const float4*)&kvs[(dg * 4 + j) * 32 + c8 + 4];
      attn[0] += qs * kv0.x; attn[1] += qs * kv0.y; attn[2] += qs * kv0.z; attn[3] += qs * kv0.w;
      attn[4] += qs * kv1.x; attn[5] += qs * kv1.y; attn[6] += qs * kv1.z; attn[7] += qs * kv1.w;
    }
  }
  float4 r0, r1;
  r0.x = attn[0] * z + accv[0]; r0.y = attn[1] * z + accv[1];
  r0.z = attn[2] * z + accv[2]; r0.w = attn[3] * z + accv[3];
  r1.x = attn[4] * z + accv[4]; r1.y = attn[5] * z + accv[5];
  r1.z = attn[6] * z + accv[6]; r1.w = attn[7] * z + accv[7];
  *(float4*)(out + rowoff + c8) = r0;
  *(float4*)(out + rowoff + c8 + 4) = r1;
}

// ---------------- launch ----------------
extern "C" void kernel_launch(void* const* d_in, const int* in_sizes, int n_in,
                              void* d_out, int out_size, void* d_ws, size_t ws_size,
                              hipStream_t stream) {
  const float* x      = (const float*)d_in[0];
  // d_in[1]=h, d_in[2]=w (ints, fixed 64 — hardcoded)
  const float* Wqk    = (const float*)d_in[3];
  const float* bqk    = (const float*)d_in[4];
  const float* lepe_w = (const float*)d_in[5];
  const float* lepe_b = (const float*)d_in[6];
  float* out = (float*)d_out;

  if (ws_size < WS_NEED) return;

  char* ws = (char*)d_ws;
  float* ksum            = (float*)(ws + OFF_KSUM);
  float* kv              = (float*)(ws + OFF_KV);
  unsigned short* xb     = (unsigned short*)(ws + OFF_XB);
  unsigned short* wT     = (unsigned short*)(ws + OFF_WT);
  unsigned short* qp     = (unsigned short*)(ws + OFF_QP);
  unsigned short* kr     = (unsigned short*)(ws + OFF_KR);
  float2* trig           = (float2*)(ws + OFF_TRIG);
  float* wt9             = (float*)(ws + OFF_WT9);
  // kv partials scratch: use d_out (16.8 MB < out_size; fully overwritten by out5 afterwards)
  float* part            = (float*)d_out;

  hipLaunchKernelGGL(prep_x_kernel, dim3(2048), dim3(256), 0, stream, x, xb);
  hipLaunchKernelGGL(prep_misc_kernel, dim3(256), dim3(256), 0, stream,
                     Wqk, lepe_w, (float*)ws, wT, trig, wt9);
  hipLaunchKernelGGL(gemm_kernel, dim3(4, MROWS / 256), dim3(512), 0, stream,
                     xb, wT, bqk, trig, qp, kr, ksum);
  hipLaunchKernelGGL(kvpart_kernel, dim3(BATCH * KV_CHUNKS), dim3(256), 0, stream,
                     kr, xb, part);
  hipLaunchKernelGGL(kvred_kernel, dim3(KV_OUT / 256), dim3(256), 0, stream,
                     part, kv);
  hipLaunchKernelGGL(out5_kernel, dim3(64, 16, 8), dim3(256), 0, stream,
                     qp, ksum, kv, trig, xb, wt9, lepe_b, out);
}